// Round 3
// baseline (2131.561 us; speedup 1.0000x reference)
//
#include <hip/hip_runtime.h>
#include <cstdint>

typedef short s16x8 __attribute__((ext_vector_type(8)));
typedef float f32x4 __attribute__((ext_vector_type(4)));
typedef unsigned short u16;

__device__ __forceinline__ u16 f2bf(float f) {
  unsigned u = __float_as_uint(f);
  u += 0x7fffu + ((u >> 16) & 1u);
  return (u16)(u >> 16);
}
__device__ __forceinline__ float bf2f(u16 h) {
  return __uint_as_float(((unsigned)h) << 16);
}
__device__ __forceinline__ unsigned pk2(float a, float b) {
  return (unsigned)f2bf(a) | ((unsigned)f2bf(b) << 16);
}

#define GLL16(g, l)                                                            \
  __builtin_amdgcn_global_load_lds(                                            \
      (const __attribute__((address_space(1))) void*)(g),                      \
      (__attribute__((address_space(3))) void*)(l), 16, 0, 0)

// ---------------- fp32 -> bf16 converts ----------------
__global__ __launch_bounds__(256) void cvt_kvin_k(const float* __restrict__ th,
                                                  const float* __restrict__ hs,
                                                  u16* __restrict__ dst) {
  int row = blockIdx.x;              // 0..33279  (b*8320 + pos)
  int b = row / 8320;
  int pos = row - b * 8320;
  const float* src = (pos < 8192) ? (th + ((size_t)b * 8192 + pos) * 4096)
                                  : (hs + ((size_t)b * 128 + (pos - 8192)) * 4096);
  u16* d = dst + (size_t)row * 4096;
#pragma unroll
  for (int i = 0; i < 4; ++i) {
    int e = (threadIdx.x + i * 256) * 4;
    float4 v = *(const float4*)(src + e);
    ushort4 o = {f2bf(v.x), f2bf(v.y), f2bf(v.z), f2bf(v.w)};
    *(ushort4*)(d + e) = o;
  }
}

__global__ __launch_bounds__(256) void cvt_w_k(const float* __restrict__ src,
                                               u16* __restrict__ dst, int n4) {
  for (int i = blockIdx.x * 256 + threadIdx.x; i < n4; i += gridDim.x * 256) {
    float4 v = *(const float4*)(src + (size_t)i * 4);
    ushort4 o = {f2bf(v.x), f2bf(v.y), f2bf(v.z), f2bf(v.w)};
    *(ushort4*)(dst + (size_t)i * 4) = o;
  }
}

// ---------------- GEMM: C[M,N] = A[M,K] @ B[N,K]^T, bf16 in, OT out ----------
// m97 structure: 128x128 tile, BK=32, 4 waves, global_load_lds(16B) staging.
template <typename OT>
__global__ __launch_bounds__(256) void gemm_bt_k(const u16* __restrict__ A, long ABS,
                                                 const u16* __restrict__ B,
                                                 OT* __restrict__ C,
                                                 int M, int N, int K) {
  __shared__ u16 As[128 * 32];
  __shared__ u16 Bs[128 * 32];
  int nb_cnt = N >> 7;
  int bid = blockIdx.x;
  int cpx = gridDim.x >> 3;                       // grid % 8 == 0 always here
  int swz = (bid & 7) * cpx + (bid >> 3);         // XCD-aware swizzle (T1)
  int mb = swz / nb_cnt, nb = swz - mb * nb_cnt;
  int t = threadIdx.x;
  int w = t >> 6, l = t & 63, g = l >> 4, c = l & 15;
  int wr = w >> 1, wc = w & 1;
  f32x4 acc[4][4] = {};
  const u16* Abase = A + (size_t)mb * ABS * K;
  const u16* Bbase = B + (size_t)nb * 128 * K;
  for (int k0 = 0; k0 < K; k0 += 32) {
    __syncthreads();
#pragma unroll
    for (int r = 0; r < 2; ++r) {
      int f = r * 256 + t;
      int row = f >> 2, sl = f & 3;
      GLL16(Abase + (size_t)row * K + k0 + sl * 8, &As[f * 8]);
    }
#pragma unroll
    for (int r = 0; r < 2; ++r) {
      int f = r * 256 + t;
      int row = f >> 2, sl = f & 3;
      GLL16(Bbase + (size_t)row * K + k0 + sl * 8, &Bs[f * 8]);
    }
    asm volatile("s_waitcnt vmcnt(0)" ::: "memory");
    __syncthreads();
    s16x8 af[4], bfr[4];
#pragma unroll
    for (int i = 0; i < 4; ++i)
      af[i] = *(const s16x8*)(As + (wr * 64 + i * 16 + c) * 32 + g * 8);
#pragma unroll
    for (int j = 0; j < 4; ++j)
      bfr[j] = *(const s16x8*)(Bs + (wc * 64 + j * 16 + c) * 32 + g * 8);
#pragma unroll
    for (int i = 0; i < 4; ++i)
#pragma unroll
      for (int j = 0; j < 4; ++j)
        acc[i][j] = __builtin_amdgcn_mfma_f32_16x16x32_bf16(af[i], bfr[j], acc[i][j], 0, 0, 0);
  }
#pragma unroll
  for (int i = 0; i < 4; ++i)
#pragma unroll
    for (int j = 0; j < 4; ++j)
#pragma unroll
      for (int r = 0; r < 4; ++r) {
        size_t row = (size_t)mb * 128 + wr * 64 + i * 16 + g * 4 + r;
        size_t col = (size_t)nb * 128 + wc * 64 + j * 16 + c;
        float v = acc[i][j][r];
        if constexpr (sizeof(OT) == 2) C[row * N + col] = f2bf(v);
        else C[row * N + col] = v;
      }
}

// ---------------- Q epilogue: RMSNorm + RoPE -> q_b[b][h][q][d] -------------
__global__ __launch_bounds__(256) void q_epi_k(const u16* __restrict__ qt,
                                               const float* __restrict__ cosp,
                                               const float* __restrict__ sinp,
                                               const float* __restrict__ nw,
                                               u16* __restrict__ qb) {
  int rid = blockIdx.x * 4 + (threadIdx.x >> 6);  // (b*128+q)*32 + h
  int l = threadIdx.x & 63;
  int b = rid >> 12;
  int q = (rid >> 5) & 127;
  int h = rid & 31;
  const u16* src = qt + ((size_t)(b * 128 + q)) * 4096 + h * 128;
  float x1 = bf2f(src[l]), x2 = bf2f(src[l + 64]);
  float ss = x1 * x1 + x2 * x2;
#pragma unroll
  for (int m = 1; m < 64; m <<= 1) ss += __shfl_xor(ss, m);
  float rn = rsqrtf(ss * (1.f / 128.f) + 1e-6f);
  float y1 = x1 * rn * nw[l];
  float y2 = x2 * rn * nw[l + 64];
  size_t cidx = ((size_t)b * 8320 + 8192 + q) * 128;
  float o1 = y1 * cosp[cidx + l] - y2 * sinp[cidx + l];
  float o2 = y2 * cosp[cidx + l + 64] + y1 * sinp[cidx + l + 64];
  u16* dst = qb + ((size_t)(b * 32 + h) * 128 + q) * 128;
  dst[l] = f2bf(o1);
  dst[l + 64] = f2bf(o2);
}

// ---------------- KV epilogue: K RMSNorm+RoPE, V copy -----------------------
__global__ __launch_bounds__(256) void kv_epi_k(const u16* __restrict__ kvt,
                                                const float* __restrict__ cosp,
                                                const float* __restrict__ sinp,
                                                const float* __restrict__ nw,
                                                u16* __restrict__ kb,
                                                u16* __restrict__ vb) {
  int row = blockIdx.x;               // b*8320 + pos
  int b = row / 8320;
  int pos = row - b * 8320;
  int t = threadIdx.x;
  int w = t >> 6, l = t & 63;
  const u16* src = kvt + (size_t)row * 2048;
  size_t cidx = ((size_t)b * 8320 + pos) * 128;
#pragma unroll
  for (int i = 0; i < 2; ++i) {
    int hh = w + i * 4;
    float x1 = bf2f(src[hh * 128 + l]), x2 = bf2f(src[hh * 128 + l + 64]);
    float ss = x1 * x1 + x2 * x2;
#pragma unroll
    for (int m = 1; m < 64; m <<= 1) ss += __shfl_xor(ss, m);
    float rn = rsqrtf(ss * (1.f / 128.f) + 1e-6f);
    float y1 = x1 * rn * nw[l], y2 = x2 * rn * nw[l + 64];
    u16* dst = kb + ((size_t)(b * 8 + hh) * 8320 + pos) * 128;
    dst[l] = f2bf(y1 * cosp[cidx + l] - y2 * sinp[cidx + l]);
    dst[l + 64] = f2bf(y2 * cosp[cidx + l + 64] + y1 * sinp[cidx + l + 64]);
  }
  int d4 = t * 4;
  int kvh = d4 >> 7, d = d4 & 127;
  ushort4 v = *(const ushort4*)(src + 1024 + d4);
  *(ushort4*)(vb + ((size_t)(b * 8 + kvh) * 8320 + pos) * 128 + d) = v;
}

// ---------------- V transpose into per-64-tile [d][kv] layout ----------------
__global__ __launch_bounds__(256) void v_trans_k(const u16* __restrict__ vb,
                                                 u16* __restrict__ vt) {
  __shared__ u16 S[64 * 136];
  int bid = blockIdx.x;
  int tile = bid % 130;
  int bk = bid / 130;
  const u16* src = vb + (size_t)bk * 8320 * 128 + (size_t)tile * 64 * 128;
  u16* dst = vt + (size_t)bk * 130 * 8192 + (size_t)tile * 8192;
  int t = threadIdx.x;
#pragma unroll
  for (int r = 0; r < 4; ++r) {
    int f = r * 256 + t;
    int pos = f >> 4, d0 = (f & 15) * 8;
    *(s16x8*)(&S[pos * 136 + d0]) = *(const s16x8*)(src + pos * 128 + d0);
  }
  __syncthreads();
#pragma unroll
  for (int r = 0; r < 4; ++r) {
    int f = r * 256 + t;
    int d = f >> 3, kv0 = (f & 7) * 8;
    s16x8 o;
#pragma unroll
    for (int j = 0; j < 8; ++j) o[j] = S[(kv0 + j) * 136 + d];
    *(s16x8*)(dst + d * 64 + kv0) = o;
  }
}

// ---------------- Flash attention (swapped QK^T, online softmax) ------------
#define ATT_SCALE 0.08838834764831845f
__global__ __launch_bounds__(256) void attn_k(const u16* __restrict__ qb,
                                              const u16* __restrict__ kb,
                                              const u16* __restrict__ vtb,
                                              u16* __restrict__ ob) {
  __shared__ u16 Ks[64 * 128];     // [kv][d], XOR-swizzled rows (256B)
  __shared__ u16 VTs[128 * 64];    // [d][kv], XOR-swizzled rows (128B)
  __shared__ u16 Plds[4][16 * 64]; // per-wave P [q][kv], swizzled
  int bid0 = blockIdx.x;
  int bid = (bid0 & 7) * 32 + (bid0 >> 3);   // XCD swizzle: K/V sharers colocate
  int qh = bid & 1, h = (bid >> 1) & 31, b = bid >> 6, kvh = h >> 2;
  int t = threadIdx.x, w = t >> 6, l = t & 63, g = l >> 4, c = l & 15;
  const u16* qbase = qb + ((size_t)(b * 32 + h) * 128 + qh * 64 + w * 16 + c) * 128;
  s16x8 qf[4];
#pragma unroll
  for (int kk = 0; kk < 4; ++kk) qf[kk] = *(const s16x8*)(qbase + kk * 32 + g * 8);
  f32x4 acc_o[8] = {};
  float m_run = -INFINITY, l_run = 0.f;
  const u16* kt = kb + (size_t)(b * 8 + kvh) * 8320 * 128;
  const u16* vt = vtb + (size_t)(b * 8 + kvh) * 130 * 8192;
  for (int tile = 0; tile < 130; ++tile) {
    __syncthreads();
    const u16* ksrc = kt + (size_t)tile * 8192;
    const u16* vsrc = vt + (size_t)tile * 8192;
#pragma unroll
    for (int r = 0; r < 4; ++r) {      // K: 64 rows x 256B, inverse-swz source
      int f = r * 256 + t;
      int row = f >> 4, sl = f & 15;
      GLL16(ksrc + row * 128 + (sl ^ (row & 7)) * 8, &Ks[f * 8]);
    }
#pragma unroll
    for (int r = 0; r < 4; ++r) {      // V^T: 128 rows x 128B
      int f = r * 256 + t;
      int row = f >> 3, sl = f & 7;
      GLL16(vsrc + row * 64 + (sl ^ (row & 7)) * 8, &VTs[f * 8]);
    }
    asm volatile("s_waitcnt vmcnt(0)" ::: "memory");
    __syncthreads();
    // S^T[kv][q] = K @ Q^T : lane holds q=c, kv rows g*4+r per 16-frag
    f32x4 accs[4] = {};
#pragma unroll
    for (int kvf = 0; kvf < 4; ++kvf) {
      int row = kvf * 16 + c;
#pragma unroll
      for (int kk = 0; kk < 4; ++kk) {
        s16x8 kf = *(const s16x8*)(&Ks[row * 128 + ((kk * 32 + g * 8) ^ ((row & 7) << 3))]);
        accs[kvf] = __builtin_amdgcn_mfma_f32_16x16x32_bf16(kf, qf[kk], accs[kvf], 0, 0, 0);
      }
    }
    float sv[16];
    float smax = -INFINITY;
#pragma unroll
    for (int kvf = 0; kvf < 4; ++kvf)
#pragma unroll
      for (int r = 0; r < 4; ++r) {
        float s = accs[kvf][r] * ATT_SCALE;
        sv[kvf * 4 + r] = s;
        smax = fmaxf(smax, s);
      }
    smax = fmaxf(smax, __shfl_xor(smax, 16));
    smax = fmaxf(smax, __shfl_xor(smax, 32));
    float m_new = fmaxf(m_run, smax);
    float corr = __expf(m_run - m_new);   // first tile: exp(-inf)=0
    float psum = 0.f;
#pragma unroll
    for (int kvf = 0; kvf < 4; ++kvf)
#pragma unroll
      for (int p = 0; p < 2; ++p) {
        float p0 = __expf(sv[kvf * 4 + 2 * p] - m_new);
        float p1 = __expf(sv[kvf * 4 + 2 * p + 1] - m_new);
        psum += p0 + p1;
        *(unsigned*)(&Plds[w][c * 64 + ((kvf * 16 + g * 4 + p * 2) ^ ((c & 7) << 3))]) =
            pk2(p0, p1);
      }
    psum += __shfl_xor(psum, 16);
    psum += __shfl_xor(psum, 32);
    l_run = l_run * corr + psum;
    m_run = m_new;
    float fr[4];
#pragma unroll
    for (int r = 0; r < 4; ++r) fr[r] = __shfl(corr, g * 4 + r);
#pragma unroll
    for (int df = 0; df < 8; ++df)
#pragma unroll
      for (int r = 0; r < 4; ++r) acc_o[df][r] *= fr[r];
    // PV: O[q][d] += P[q][kv] @ V[kv][d]
    s16x8 pf0 = *(const s16x8*)(&Plds[w][c * 64 + ((g * 8) ^ ((c & 7) << 3))]);
    s16x8 pf1 = *(const s16x8*)(&Plds[w][c * 64 + ((32 + g * 8) ^ ((c & 7) << 3))]);
#pragma unroll
    for (int df = 0; df < 8; ++df) {
      int vrow = df * 16 + c;
      s16x8 v0 = *(const s16x8*)(&VTs[vrow * 64 + ((g * 8) ^ ((vrow & 7) << 3))]);
      s16x8 v1 = *(const s16x8*)(&VTs[vrow * 64 + ((32 + g * 8) ^ ((vrow & 7) << 3))]);
      acc_o[df] = __builtin_amdgcn_mfma_f32_16x16x32_bf16(pf0, v0, acc_o[df], 0, 0, 0);
      acc_o[df] = __builtin_amdgcn_mfma_f32_16x16x32_bf16(pf1, v1, acc_o[df], 0, 0, 0);
    }
  }
  float linv[4];
#pragma unroll
  for (int r = 0; r < 4; ++r) linv[r] = 1.f / __shfl(l_run, g * 4 + r);
  size_t orow = (size_t)b * 128 + qh * 64 + w * 16;
#pragma unroll
  for (int df = 0; df < 8; ++df)
#pragma unroll
    for (int r = 0; r < 4; ++r)
      ob[(orow + g * 4 + r) * 4096 + h * 128 + df * 16 + c] = f2bf(acc_o[df][r] * linv[r]);
}

// ---------------- launch ----------------
extern "C" void kernel_launch(void* const* d_in, const int* in_sizes, int n_in,
                              void* d_out, int out_size, void* d_ws, size_t ws_size,
                              hipStream_t stream) {
  const float* hs = (const float*)d_in[0];
  const float* th = (const float*)d_in[1];
  const float* cosp = (const float*)d_in[2];
  const float* sinp = (const float*)d_in[3];
  const float* Wq = (const float*)d_in[4];
  const float* Wk = (const float*)d_in[5];
  const float* Wv = (const float*)d_in[6];
  const float* Wo = (const float*)d_in[7];
  const float* qnw = (const float*)d_in[8];
  const float* knw = (const float*)d_in[9];
  char* ws = (char*)d_ws;
  // region plan (bytes); kb/vb/vt alias the kvin region after GEMMs are done
  u16* kvin = (u16*)(ws + 0);             // 272,629,760 B
  u16* kb   = (u16*)(ws + 68157440);      // 68,157,440 B
  u16* vb   = (u16*)(ws + 136314880);     // 68,157,440 B
  u16* vt   = (u16*)(ws + 0);             // 68,157,440 B
  u16* wq   = (u16*)(ws + 272629760);     // 33,554,432 B
  u16* wkv  = (u16*)(ws + 306184192);     // 16,777,216 B
  u16* wo   = (u16*)(ws + 322961408);     // 33,554,432 B
  u16* kvt  = (u16*)(ws + 356515840);     // 136,314,880 B
  u16* qt   = (u16*)(ws + 492830720);     // 4,194,304 B
  u16* qbuf = (u16*)(ws + 497025024);     // 4,194,304 B
  u16* ao   = (u16*)(ws + 501219328);     // 4,194,304 B  (total ~505.4 MB)
  float* outp = (float*)d_out;

  cvt_kvin_k<<<33280, 256, 0, stream>>>(th, hs, kvin);
  cvt_w_k<<<4096, 256, 0, stream>>>(Wq, wq, 16777216 / 4);
  cvt_w_k<<<2048, 256, 0, stream>>>(Wk, wkv, 4194304 / 4);
  cvt_w_k<<<2048, 256, 0, stream>>>(Wv, wkv + 4194304, 4194304 / 4);
  cvt_w_k<<<4096, 256, 0, stream>>>(Wo, wo, 16777216 / 4);
  // KV projection: [33280,4096] @ [2048,4096]^T
  gemm_bt_k<u16><<<4160, 256, 0, stream>>>(kvin, 128, wkv, kvt, 33280, 2048, 4096);
  // Q projection: hidden rows live inside kvin at b*8320+8192..; ABS=8320
  gemm_bt_k<u16><<<128, 256, 0, stream>>>(kvin + (size_t)8192 * 4096, 8320, wq, qt,
                                          512, 4096, 4096);
  q_epi_k<<<4096, 256, 0, stream>>>(qt, cosp, sinp, qnw, qbuf);
  kv_epi_k<<<33280, 256, 0, stream>>>(kvt, cosp, sinp, knw, kb, vb);
  v_trans_k<<<4160, 256, 0, stream>>>(vb, vt);
  attn_k<<<256, 256, 0, stream>>>(qbuf, kb, vt, ao);
  // O projection -> fp32 output
  gemm_bt_k<float><<<128, 256, 0, stream>>>(ao, 128, wo, outp, 512, 4096, 4096);
}